// Round 2
// baseline (1604.019 us; speedup 1.0000x reference)
//
#include <hip/hip_runtime.h>
#include <cmath>

#define HE_N_LEVELS 16
#define HE_LOG2_HASH 19
#define HE_HASHMAP_SIZE (1u << HE_LOG2_HASH)
#define HE_HASH_MASK (HE_HASHMAP_SIZE - 1u)
#define HE_P1 2654435761u
#define HE_P2 805459861u

struct HEParams {
    int      res[HE_N_LEVELS];
    float    resf[HE_N_LEVELS];
    unsigned dense_bits;   // bit l set => dense indexing ((res+1)^3 <= HASHMAP_SIZE)
};

__global__ __launch_bounds__(256) void he_encode_kernel(
    const float* __restrict__ pos,     // [N, 3]
    const float* __restrict__ emb,     // [16, HASHMAP_SIZE, 2]
    float* __restrict__ out,           // [N, 32]
    int n, HEParams prm)
{
    __shared__ float spos[256 * 3];
    const int tid   = threadIdx.x;
    const int bbase = blockIdx.x * 256;

    // Coalesced staged load of this block's 256 positions (768 floats).
    #pragma unroll
    for (int i = 0; i < 3; ++i) {
        const int g = bbase * 3 + tid + i * 256;
        if (g < n * 3) spos[tid + i * 256] = pos[g];
    }
    __syncthreads();

    const int p = bbase + tid;
    if (p >= n) return;

    const float x = spos[tid * 3 + 0];
    const float y = spos[tid * 3 + 1];
    const float z = spos[tid * 3 + 2];

    float outv[32];

    #pragma unroll
    for (int l = 0; l < HE_N_LEVELS; ++l) {
        const float rf = prm.resf[l];
        const float sx = x * rf, sy = y * rf, sz = z * rf;
        const float fx = floorf(sx), fy = floorf(sy), fz = floorf(sz);
        const float wx = sx - fx, wy = sy - fy, wz = sz - fz;
        const int vx = (int)fx, vy = (int)fy, vz = (int)fz;

        unsigned idx[8];
        if (prm.dense_bits & (1u << l)) {
            // dense: idx = cx*r1^2 + cy*r1 + cz, corner order (i,j,k) k fastest
            const int r1  = prm.res[l] + 1;
            const int r1s = r1 * r1;
            const int base = vx * r1s + vy * r1 + vz;
            idx[0] = base;             idx[1] = base + 1;
            idx[2] = base + r1;        idx[3] = base + r1 + 1;
            idx[4] = base + r1s;       idx[5] = base + r1s + 1;
            idx[6] = base + r1s + r1;  idx[7] = base + r1s + r1 + 1;
        } else {
            // hash: (cx*1) ^ (cy*P1) ^ (cz*P2), masked. Only 2 real mults.
            const unsigned hx0 = (unsigned)vx,        hx1 = hx0 + 1u;
            const unsigned hy0 = (unsigned)vy * HE_P1, hy1 = hy0 + HE_P1;
            const unsigned hz0 = (unsigned)vz * HE_P2, hz1 = hz0 + HE_P2;
            const unsigned t00 = hy0 ^ hz0, t01 = hy0 ^ hz1;
            const unsigned t10 = hy1 ^ hz0, t11 = hy1 ^ hz1;
            idx[0] = (hx0 ^ t00) & HE_HASH_MASK;
            idx[1] = (hx0 ^ t01) & HE_HASH_MASK;
            idx[2] = (hx0 ^ t10) & HE_HASH_MASK;
            idx[3] = (hx0 ^ t11) & HE_HASH_MASK;
            idx[4] = (hx1 ^ t00) & HE_HASH_MASK;
            idx[5] = (hx1 ^ t01) & HE_HASH_MASK;
            idx[6] = (hx1 ^ t10) & HE_HASH_MASK;
            idx[7] = (hx1 ^ t11) & HE_HASH_MASK;
        }

        const float2* __restrict__ tab =
            (const float2*)emb + (size_t)l * HE_HASHMAP_SIZE;

        // 8 independent gathers — issue together, wait once.
        const float2 f000 = tab[idx[0]];
        const float2 f001 = tab[idx[1]];
        const float2 f010 = tab[idx[2]];
        const float2 f011 = tab[idx[3]];
        const float2 f100 = tab[idx[4]];
        const float2 f101 = tab[idx[5]];
        const float2 f110 = tab[idx[6]];
        const float2 f111 = tab[idx[7]];

        const float omx = 1.f - wx, omy = 1.f - wy, omz = 1.f - wz;

        const float c00a = f000.x * omx + f100.x * wx;
        const float c00b = f000.y * omx + f100.y * wx;
        const float c01a = f001.x * omx + f101.x * wx;
        const float c01b = f001.y * omx + f101.y * wx;
        const float c10a = f010.x * omx + f110.x * wx;
        const float c10b = f010.y * omx + f110.y * wx;
        const float c11a = f011.x * omx + f111.x * wx;
        const float c11b = f011.y * omx + f111.y * wx;

        const float c0a = c00a * omy + c10a * wy;
        const float c0b = c00b * omy + c10b * wy;
        const float c1a = c01a * omy + c11a * wy;
        const float c1b = c01b * omy + c11b * wy;

        outv[2 * l]     = c0a * omz + c1a * wz;
        outv[2 * l + 1] = c0b * omz + c1b * wz;
    }

    // 128B contiguous per thread, 8 x float4.
    float4* __restrict__ o4 = (float4*)(out + (size_t)p * 32);
    #pragma unroll
    for (int i = 0; i < 8; ++i)
        o4[i] = make_float4(outv[4 * i + 0], outv[4 * i + 1],
                            outv[4 * i + 2], outv[4 * i + 3]);
}

extern "C" void kernel_launch(void* const* d_in, const int* in_sizes, int n_in,
                              void* d_out, int out_size, void* d_ws, size_t ws_size,
                              hipStream_t stream) {
    const float* pos = (const float*)d_in[0];
    const float* emb = (const float*)d_in[1];
    float*       out = (float*)d_out;
    const int n = in_sizes[0] / 3;

    // Level params in host double math, matching numpy exactly.
    HEParams prm;
    const double scale = std::exp((std::log(2048.0) - std::log(16.0)) / 15.0);
    prm.dense_bits = 0u;
    for (int l = 0; l < HE_N_LEVELS; ++l) {
        const int r = (int)std::floor(16.0 * std::pow(scale, (double)l));
        prm.res[l]  = r;
        prm.resf[l] = (float)r;
        const long long r1 = (long long)r + 1;
        if (r1 * r1 * r1 <= (long long)HE_HASHMAP_SIZE) prm.dense_bits |= (1u << l);
    }

    const int nblocks = (n + 255) / 256;
    hipLaunchKernelGGL(he_encode_kernel, dim3(nblocks), dim3(256), 0, stream,
                       pos, emb, out, n, prm);
}